// Round 12
// baseline (319.447 us; speedup 1.0000x reference)
//
#include <hip/hip_runtime.h>
#include <hip/hip_fp16.h>
#include <cmath>

#define EPS 1e-5f
#define TAU 0.15f
#define RQ  32
#define MAXC 64

// Problem constants (fixed instance)
#define Bn 16
#define Dn 256
#define Tn 4096
#define Kn 2048

typedef unsigned short ushort_t;
typedef __attribute__((ext_vector_type(8))) _Float16 f16x8;
typedef __attribute__((ext_vector_type(4))) float f32x4;

__device__ __forceinline__ unsigned short f2h(float v) {
    return __half_as_ushort(__float2half_rn(v));
}

#define GLOAD_LDS16(gp, lp) __builtin_amdgcn_global_load_lds( \
    (const __attribute__((address_space(1))) unsigned int*)(gp), \
    (__attribute__((address_space(3))) unsigned int*)(lp), 16, 0, 0)

// ---------------------------------------------------------------------------
// Kernel 1: prep — emb = es/max(usage,eps); e16 fp16 plane; bias = 0.5|e|^2;
// embT4 transpose (embT4 now unused by rescue but kept harmless... removed).
// ---------------------------------------------------------------------------
__global__ __launch_bounds__(256) void prep_kernel(
    const float* __restrict__ es, const float* __restrict__ usage,
    float* __restrict__ emb, ushort_t* __restrict__ e16,
    float* __restrict__ bias, int* __restrict__ counter)
{
    __shared__ float wsum[4];
    const int k = blockIdx.x;
    const int d = threadIdx.x;
    const float inv = 1.0f / fmaxf(usage[k], EPS);
    const float v = es[(size_t)k * Dn + d] * inv;
    emb[(size_t)k * Dn + d] = v;
    e16[(size_t)k * Dn + d] = f2h(fminf(fmaxf(v, -65504.f), 65504.f));
    float sq = v * v;
    #pragma unroll
    for (int off = 32; off > 0; off >>= 1) sq += __shfl_down(sq, off, 64);
    const int lane = d & 63, wv = d >> 6;
    if (lane == 0) wsum[wv] = sq;
    __syncthreads();
    if (d == 0) {
        bias[k] = 0.5f * (wsum[0] + wsum[1] + wsum[2] + wsum[3]);
        if (k == 0) *counter = 0;
    }
}

// ---------------------------------------------------------------------------
// Kernel 3 (R11 VERBATIM + slist export): verified fused gemm+decode.
// 256t tile/block, 8 waves x 32t, A in regs from x, 2x32 KB XOR-swizzled
// double-buffered B, counted vmcnt, grid 256 = 1/CU.  Epilogue: codes +
// decoded columns + rescue list; NEW: also stores S1 (fp32 winner score)
// per rescued point for the candidate-filtered rescue.
// ---------------------------------------------------------------------------
#define BARRIER_PIN()                                                         \
    __builtin_amdgcn_s_barrier();                                             \
    __builtin_amdgcn_sched_barrier(0)

// stage 32 KB B-chunk (128 k x 128 d half) with inverse-swizzled source
#define STAGE_B(dst, kcc, hh)                                                 \
    {                                                                         \
        _Pragma("unroll")                                                     \
        for (int r = 0; r < 4; ++r) {                                         \
            const int c   = r * 512 + tid;                                    \
            const int row = c >> 4;                                           \
            const int col = (((c & 15) ^ (row & 15)) << 3);                   \
            GLOAD_LDS16(e16 + ((size_t)((kcc) * 128 + row)) * Dn + (hh) * 128 + col, \
                        (dst) + ((r * 512 + (wid << 6)) << 3));               \
        }                                                                     \
    }

// plain accumulate phase (d-half via afArr, B from bbuf)
#define COMPUTE_ACC(bbuf, afArr)                                              \
    {                                                                         \
        __builtin_amdgcn_s_setprio(1);                                        \
        _Pragma("unroll")                                                     \
        for (int ks = 0; ks < 4; ++ks)                                        \
            _Pragma("unroll")                                                 \
            for (int j = 0; j < 8; ++j) {                                     \
                const f16x8 bf = *(const f16x8*)(                             \
                    &(bbuf)[((j << 4) + l15) * 128 +                          \
                            ((((ks << 2) | quad) ^ l15) << 3)]);              \
                _Pragma("unroll")                                             \
                for (int i = 0; i < 2; ++i)                                   \
                    acc[i][j] = __builtin_amdgcn_mfma_f32_16x16x32_f16(       \
                        afArr[ks * 2 + i], bf, acc[i][j], 0, 0, 0);           \
            }                                                                 \
        __builtin_amdgcn_s_setprio(0);                                        \
    }

__global__ __launch_bounds__(512, 2) void gemm_argmax(
    const float* __restrict__ x, const ushort_t* __restrict__ e16,
    const float* __restrict__ bias_g, const float* __restrict__ emb,
    int* __restrict__ codes_i, float* __restrict__ codes_f,
    int* __restrict__ list, float* __restrict__ slist,
    int* __restrict__ counter, float* __restrict__ decoded)
{
    __shared__ __align__(16) ushort_t BsS[2][128 * 128]; // 2 x 32 KB
    __shared__ __align__(16) float    biasLds[2048];     // 8 KB
    __shared__ int codeLds[256];                         // 1 KB

    const int bid = blockIdx.x;          // 256 blocks: one 256-t tile each
    const int b   = bid >> 4;
    const int tt  = bid & 15;
    const int t0  = tt << 8;

    const int tid  = threadIdx.x;
    const int lane = tid & 63;
    const int wid  = tid >> 6;           // 8 waves, each owns 32 t-rows
    const int l15  = lane & 15;
    const int quad = lane >> 4;
    const int wm   = wid;                // t-block of 32 rows

    const size_t bTt0 = (size_t)b * Tn + t0;

    // ---- prologue: bias -> LDS; A -> registers directly from x ----
    GLOAD_LDS16(bias_g + (tid << 2), biasLds + (wid << 8));   // 1 outstanding

    // persistent A fragments: 2 halves x (4 ks x 2 i) = 16 f16x8 = 64 VGPR
    f16x8 af0[8], af1[8];
    {
        const float* xb = x + (size_t)b * Dn * Tn;   // [D][T]
        #pragma unroll
        for (int ks = 0; ks < 4; ++ks)
            #pragma unroll
            for (int i = 0; i < 2; ++i) {
                const int t = t0 + (wm << 5) + (i << 4) + l15;
                const float* c0 = xb + ((size_t)(ks * 32 + quad * 8)) * Tn + t;
                const float* c1 = c0 + (size_t)128 * Tn;
                f16x8 v0, v1;
                #pragma unroll
                for (int e = 0; e < 8; ++e) {
                    v0[e] = (_Float16)c0[(size_t)e * Tn];
                    v1[e] = (_Float16)c1[(size_t)e * Tn];
                }
                af0[ks * 2 + i] = v0;
                af1[ks * 2 + i] = v1;
            }
    }

    // accumulators: 2 i x 8 j = 64 regs
    f32x4 acc[2][8];
    // top-2 state per (i,r): 24 regs
    float S1[2][4], S2[2][4];
    int   K1[2][4];
    #pragma unroll
    for (int i = 0; i < 2; ++i)
        #pragma unroll
        for (int r = 0; r < 4; ++r) { S1[i][r] = -INFINITY; S2[i][r] = -INFINITY; K1[i][r] = 0; }
    #pragma unroll
    for (int i = 0; i < 2; ++i)
        #pragma unroll
        for (int j = 0; j < 8; ++j)
            acc[i][j] = (f32x4){-INFINITY, -INFINITY, -INFINITY, -INFINITY};

    asm volatile("s_waitcnt vmcnt(0)" ::: "memory");   // bias + A loads landed
    BARRIER_PIN();                                     // biasLds visible
    STAGE_B(&BsS[0][0], 0, 0);                         // 4
    STAGE_B(&BsS[1][0], 0, 1);                         // 4 -> 8 outstanding

    #pragma unroll 1
    for (int kc = 0; kc < 16; ++kc) {
        // ---- phase h0 (d 0..127, Bs0): drain prev-kc acc + C=-bias re-init --
        asm volatile("s_waitcnt vmcnt(4)" ::: "memory");
        BARRIER_PIN();
        {
            float bj[8];
            #pragma unroll
            for (int j = 0; j < 8; ++j)
                bj[j] = biasLds[(kc << 7) + (j << 4) + l15];
            const int kdrb = ((kc - 1) << 7) + l15;   // k of drained values
            __builtin_amdgcn_s_setprio(1);
            #pragma unroll
            for (int j = 0; j < 8; ++j) {
                const f16x8 bf0 = *(const f16x8*)(
                    &BsS[0][((j << 4) + l15) * 128 + ((quad ^ l15) << 3)]);
                const float nb = -bj[j];
                const f32x4 cin = {nb, nb, nb, nb};
                const int kdr = kdrb + (j << 4);
                #pragma unroll
                for (int i = 0; i < 2; ++i) {
                    // drain old acc[i][j]: med3 top-2 insert (kc==0: -INF, harmless)
                    #pragma unroll
                    for (int r = 0; r < 4; ++r) {
                        const float s = acc[i][j][r];
                        S2[i][r] = __builtin_amdgcn_fmed3f(s, S1[i][r], S2[i][r]);
                        const bool gt = s > S1[i][r];
                        K1[i][r] = gt ? kdr : K1[i][r];
                        S1[i][r] = fmaxf(S1[i][r], s);
                    }
                    acc[i][j] = __builtin_amdgcn_mfma_f32_16x16x32_f16(
                        af0[i], bf0, cin, 0, 0, 0);
                }
            }
            #pragma unroll
            for (int ks = 1; ks < 4; ++ks)
                #pragma unroll
                for (int j = 0; j < 8; ++j) {
                    const f16x8 bf = *(const f16x8*)(
                        &BsS[0][((j << 4) + l15) * 128 +
                                ((((ks << 2) | quad) ^ l15) << 3)]);
                    #pragma unroll
                    for (int i = 0; i < 2; ++i)
                        acc[i][j] = __builtin_amdgcn_mfma_f32_16x16x32_f16(
                            af0[ks * 2 + i], bf, acc[i][j], 0, 0, 0);
                }
            __builtin_amdgcn_s_setprio(0);
        }
        BARRIER_PIN();                       // WAR: Bs0 readers done
        if (kc < 15) STAGE_B(&BsS[0][0], kc + 1, 0);

        // ---- phase h1 (d 128..255, Bs1): plain accumulate ----
        if (kc < 15) { asm volatile("s_waitcnt vmcnt(4)" ::: "memory"); }
        else         { asm volatile("s_waitcnt vmcnt(0)" ::: "memory"); }
        BARRIER_PIN();
        COMPUTE_ACC((&BsS[1][0]), af1);
        BARRIER_PIN();                       // WAR: Bs1 readers done
        if (kc < 15) STAGE_B(&BsS[1][0], kc + 1, 1);
    }

    __builtin_amdgcn_sched_barrier(0);

    // ---- final drain of kc=15 acc ----
    {
        const int kfb = (15 << 7) + l15;
        #pragma unroll
        for (int j = 0; j < 8; ++j) {
            const int kf = kfb + (j << 4);
            #pragma unroll
            for (int i = 0; i < 2; ++i)
                #pragma unroll
                for (int r = 0; r < 4; ++r) {
                    const float s = acc[i][j][r];
                    S2[i][r] = __builtin_amdgcn_fmed3f(s, S1[i][r], S2[i][r]);
                    const bool gt = s > S1[i][r];
                    K1[i][r] = gt ? kf : K1[i][r];
                    S1[i][r] = fmaxf(S1[i][r], s);
                }
        }
    }

    // ---- butterfly across the 16 k-lanes (tie-break: lowest k) ----
    #pragma unroll
    for (int m = 1; m <= 8; m <<= 1) {
        #pragma unroll
        for (int i = 0; i < 2; ++i)
            #pragma unroll
            for (int r = 0; r < 4; ++r) {
                const float os1 = __shfl_xor(S1[i][r], m);
                const float os2 = __shfl_xor(S2[i][r], m);
                const int   ok1 = __shfl_xor(K1[i][r], m);
                const bool take = (os1 > S1[i][r]) || (os1 == S1[i][r] && ok1 < K1[i][r]);
                const float ns2 = take ? fmaxf(S1[i][r], os2) : fmaxf(S2[i][r], os1);
                if (take) { S1[i][r] = os1; K1[i][r] = ok1; }
                S2[i][r] = ns2;
            }
    }

    if (l15 == 0) {
        #pragma unroll
        for (int i = 0; i < 2; ++i)
            #pragma unroll
            for (int r = 0; r < 4; ++r) {
                const int row = (wm << 5) + (i << 4) + (quad << 2) + r;
                const size_t p = bTt0 + row;
                const int wk = K1[i][r];
                codeLds[row] = wk;
                codes_i[p] = wk;
                codes_f[p] = (float)wk;
                if (S1[i][r] - S2[i][r] < TAU) {
                    const int idx = atomicAdd(counter, 1);
                    list[idx]  = (int)p;
                    slist[idx] = S1[i][r];
                }
            }
    }
    __syncthreads();

    // ---- fused decode: this block's 256 columns of decoded[b][:, t0..] ----
    {
        const int p2 = tid & 255;
        const int dh = tid >> 8;                       // 0 or 1 (d-half)
        const int c  = codeLds[p2];
        const float4* e4 = (const float4*)(emb + (size_t)c * Dn) + dh * 32;
        float* ob = decoded + ((size_t)(b * Dn + dh * 128)) * Tn + t0 + p2;
        #pragma unroll 4
        for (int q = 0; q < 32; ++q) {
            const float4 v = e4[q];
            ob[(size_t)(q * 4 + 0) * Tn] = v.x;
            ob[(size_t)(q * 4 + 1) * Tn] = v.y;
            ob[(size_t)(q * 4 + 2) * Tn] = v.z;
            ob[(size_t)(q * 4 + 3) * Tn] = v.w;
        }
    }
}

// ---------------------------------------------------------------------------
// Kernel 5 (CANDIDATE-FILTERED RESCUE): per 32-point batch —
// (1) mini fp16-MFMA GEMM recomputes scores (same instr, same d-order, same
//     RTN cvt as main gemm -> bit-identical); candidates = {k : s > S1-TAU}
//     (the pipeline's existing TAU >= 2*eps invariant: the exact winner
//     always satisfies this).  >MAXC candidates -> safe full-scan fallback.
// (2) exact fp32 wave-dots on candidates only; packed-u64 LDS atomicMax
//     resolves winner with lowest-k tie-break.
// (3) codes + decoded-column fixup.
// ---------------------------------------------------------------------------
__global__ __launch_bounds__(256) void rescue_kernel(
    const float* __restrict__ x, const ushort_t* __restrict__ e16,
    const float* __restrict__ bias, const float* __restrict__ emb,
    const int* __restrict__ list, const float* __restrict__ slist,
    const int* __restrict__ counter, int* __restrict__ codes_i,
    float* __restrict__ codes_f, float* __restrict__ decoded)
{
    __shared__ float    xv32[RQ][256];                 // 32 KB
    __shared__ ushort_t xhs[RQ][256];                  // 16 KB
    __shared__ int      cand[RQ][MAXC];                // 8 KB
    __shared__ int      ccnt[RQ];
    __shared__ float    s1l[RQ];
    __shared__ unsigned long long best[RQ];
    __shared__ int      plist[RQ];
    __shared__ int      fcode[RQ];

    const int tid  = threadIdx.x;
    const int lane = tid & 63;
    const int wid  = tid >> 6;
    const int l15  = lane & 15;
    const int quad = lane >> 4;
    const int count = *counter;

    for (int base = blockIdx.x * RQ; base < count; base += gridDim.x * RQ) {
        const int npts = min(RQ, count - base);
        __syncthreads();                 // previous iteration's readers done
        if (tid < RQ) {
            ccnt[tid] = 0;
            best[tid] = 0ull;
            if (tid < npts) { plist[tid] = list[base + tid]; s1l[tid] = slist[base + tid]; }
            else            { plist[tid] = 0; s1l[tid] = INFINITY; }
        }
        __syncthreads();
        // gather x columns: fp32 exact + fp16 (RTN, identical to gemm A-load)
        for (int pi = 0; pi < npts; ++pi) {
            const int p = plist[pi];
            const float v = x[((size_t)((p >> 12) * Dn + tid)) * Tn + (p & 4095)];
            xv32[pi][tid] = v;
            xhs[pi][tid]  = __half_as_ushort(__float2half_rn(v));
        }
        for (int pi = npts; pi < RQ; ++pi) { xv32[pi][tid] = 0.f; xhs[pi][tid] = 0; }
        __syncthreads();

        // ---- phase 1: mini-MFMA scores for this wave's 512-k slice ----
        f16x8 af[16];   // [dstep 0..7][tile i 0..1]
        #pragma unroll
        for (int ds = 0; ds < 8; ++ds)
            #pragma unroll
            for (int i = 0; i < 2; ++i)
                af[ds * 2 + i] = *(const f16x8*)(&xhs[i * 16 + l15][ds * 32 + quad * 8]);
        float s1r[2][4];
        #pragma unroll
        for (int i = 0; i < 2; ++i)
            #pragma unroll
            for (int r = 0; r < 4; ++r)
                s1r[i][r] = s1l[i * 16 + quad * 4 + r] - TAU;

        const int kb = wid << 9;                       // wave's k-base
        for (int j = 0; j < 32; ++j) {
            const int kj = kb + (j << 4);
            const float nb = -bias[kj + l15];
            f32x4 acc0 = {nb, nb, nb, nb};
            f32x4 acc1 = {nb, nb, nb, nb};
            #pragma unroll
            for (int ds = 0; ds < 8; ++ds) {
                const f16x8 bf = *(const f16x8*)(
                    e16 + ((size_t)(kj + l15)) * Dn + ds * 32 + quad * 8);
                acc0 = __builtin_amdgcn_mfma_f32_16x16x32_f16(af[ds * 2 + 0], bf, acc0, 0, 0, 0);
                acc1 = __builtin_amdgcn_mfma_f32_16x16x32_f16(af[ds * 2 + 1], bf, acc1, 0, 0, 0);
            }
            const int kk = kj + l15;
            #pragma unroll
            for (int r = 0; r < 4; ++r) {
                if (acc0[r] > s1r[0][r]) {
                    const int pt = quad * 4 + r;
                    const int ix = atomicAdd(&ccnt[pt], 1);
                    if (ix < MAXC) cand[pt][ix] = kk;
                }
                if (acc1[r] > s1r[1][r]) {
                    const int pt = 16 + quad * 4 + r;
                    const int ix = atomicAdd(&ccnt[pt], 1);
                    if (ix < MAXC) cand[pt][ix] = kk;
                }
            }
        }
        __syncthreads();

        // ---- phase 2: exact fp32 on candidates (wave-distributed) ----
        for (int pi = 0; pi < npts; ++pi) {
            const int cc = ccnt[pi];
            const int cn = (cc > MAXC) ? Kn : cc;      // overflow -> full scan
            for (int c = wid; c < cn; c += 4) {
                const int k = (cc > MAXC) ? c : cand[pi][c];
                const float* er = emb + (size_t)k * Dn;
                float s = 0.f;
                #pragma unroll
                for (int e = 0; e < 4; ++e)
                    s += er[lane * 4 + e] * xv32[pi][lane * 4 + e];
                #pragma unroll
                for (int off = 32; off > 0; off >>= 1)
                    s += __shfl_xor(s, off);
                if (lane == 0) {
                    s -= bias[k];
                    unsigned sb = __float_as_uint(s);
                    sb = (sb & 0x80000000u) ? ~sb : (sb | 0x80000000u);
                    const unsigned long long pk =
                        ((unsigned long long)sb << 32) | (unsigned)(2047 - k);
                    atomicMax(&best[pi], pk);
                }
            }
        }
        __syncthreads();
        if (tid < npts) {
            const int k = 2047 - (int)(best[tid] & 0xFFFFFFFFu);
            fcode[tid] = k;
            const int p = plist[tid];
            codes_i[p] = k;
            codes_f[p] = (float)k;
        }
        __syncthreads();
        // decoded fixup: all 256 threads rewrite column d=tid per point
        for (int pi = 0; pi < npts; ++pi) {
            const int p = plist[pi];
            const int c = fcode[pi];
            decoded[((size_t)((p >> 12) * Dn + tid)) * Tn + (p & 4095)] =
                emb[(size_t)c * Dn + tid];
        }
    }
}

// ---------------------------------------------------------------------------
extern "C" void kernel_launch(void* const* d_in, const int* in_sizes, int n_in,
                              void* d_out, int out_size, void* d_ws, size_t ws_size,
                              hipStream_t stream) {
    const float* x     = (const float*)d_in[0];   // [B, D, T]
    const float* es    = (const float*)d_in[1];   // [K, D]
    const float* usage = (const float*)d_in[2];   // [K]

    // ws layout (byte offsets, 16-aligned) — ~6.1 MiB
    char* ws = (char*)d_ws;
    float*    emb     = (float*)(ws + 0);                // 2 MiB
    float*    bias    = (float*)(ws + 2097152);          // 8 KB
    ushort_t* e16     = (ushort_t*)(ws + 2105344);       // 1 MiB
    int*      codes_i = (int*)(ws + 5251072);            // 256 KB
    int*      list    = (int*)(ws + 5513216);            // 256 KB
    int*      counter = (int*)(ws + 5775360);            // 16 B slot
    float*    slist   = (float*)(ws + 5775376);          // 256 KB

    float* codes_f = (float*)d_out;                      // [B*T]
    float* decoded = (float*)d_out + (size_t)Bn * Tn;    // [B*D*T], 64 MiB

    prep_kernel<<<Kn, 256, 0, stream>>>(es, usage, emb, e16, bias, counter);

    // 256 blocks of 512 thr (1/CU): 256 t x full K=2048, A in regs,
    // codes + decoded + rescue list/S1 written in-kernel
    gemm_argmax<<<256, 512, 0, stream>>>(x, e16, bias, emb, codes_i, codes_f,
                                         list, slist, counter, decoded);

    rescue_kernel<<<512, 256, 0, stream>>>(x, e16, bias, emb, list, slist,
                                           counter, codes_i, codes_f, decoded);
}